// Round 2
// baseline (1842.505 us; speedup 1.0000x reference)
//
#include <hip/hip_runtime.h>
#include <math.h>

#define NTOK 16384
#define H 4096
#define NE 256
#define BM 32
#define BK 16
#define XP 34
#define EP 260

__global__ __launch_bounds__(256)
void moe_gate_kernel(const float* __restrict__ X,
                     const float* __restrict__ W,
                     const float* __restrict__ bias,
                     float* __restrict__ out)
{
    __shared__ double Xs[BK * XP];
    __shared__ double Ws[BK * EP];

    const int t = threadIdx.x;
    const int lane = t & 63;
    const int wv = t >> 6;          // wave id: owns tokens wv*8 .. wv*8+7
    const int m0 = blockIdx.x * BM;

    double acc[8][4];
    #pragma unroll
    for (int i = 0; i < 8; ++i)
        #pragma unroll
        for (int j = 0; j < 4; ++j) acc[i][j] = 0.0;

    // staging maps
    const int xm = t >> 3;          // 0..31 token within block
    const int xk = (t & 7) * 2;     // 0,2,..,14
    const int we = t >> 2;          // 0..63 expert base
    const int wk = (t & 3) * 4;     // 0,4,8,12

    const float* gx = X + (size_t)(m0 + xm) * H + xk;
    const float* gw = W + (size_t)we * H + wk;

    float2 xreg = *(const float2*)(gx);
    float4 wreg[4];
    #pragma unroll
    for (int p = 0; p < 4; ++p)
        wreg[p] = *(const float4*)(gw + (size_t)(64 * p) * H);

    const int NT = H / BK;
    for (int t0 = 0; t0 < NT; ++t0) {
        __syncthreads();
        Xs[(xk + 0) * XP + xm] = (double)xreg.x;
        Xs[(xk + 1) * XP + xm] = (double)xreg.y;
        #pragma unroll
        for (int p = 0; p < 4; ++p) {
            const int e = we + 64 * p;
            Ws[(wk + 0) * EP + e] = (double)wreg[p].x;
            Ws[(wk + 1) * EP + e] = (double)wreg[p].y;
            Ws[(wk + 2) * EP + e] = (double)wreg[p].z;
            Ws[(wk + 3) * EP + e] = (double)wreg[p].w;
        }
        __syncthreads();
        if (t0 + 1 < NT) {
            const int off = (t0 + 1) * BK;
            xreg = *(const float2*)(gx + off);
            #pragma unroll
            for (int p = 0; p < 4; ++p)
                wreg[p] = *(const float4*)(gw + (size_t)(64 * p) * H + off);
        }
        #pragma unroll
        for (int j = 0; j < BK; ++j) {
            const double* xrow = &Xs[j * XP + wv * 8];
            const double2 xa = *(const double2*)(xrow + 0);
            const double2 xb = *(const double2*)(xrow + 2);
            const double2 xc = *(const double2*)(xrow + 4);
            const double2 xd = *(const double2*)(xrow + 6);
            const double2 wa = *(const double2*)&Ws[j * EP + lane * 4];
            const double2 wb = *(const double2*)&Ws[j * EP + lane * 4 + 2];
            const double xs8[8] = {xa.x, xa.y, xb.x, xb.y, xc.x, xc.y, xd.x, xd.y};
            const double ws4[4] = {wa.x, wa.y, wb.x, wb.y};
            #pragma unroll
            for (int mi = 0; mi < 8; ++mi)
                #pragma unroll
                for (int ei = 0; ei < 4; ++ei)
                    acc[mi][ei] = fma(xs8[mi], ws4[ei], acc[mi][ei]);
        }
    }

    // ---- routing epilogue: wave wv owns tokens m0+wv*8+tt; lane owns experts lane*4..lane*4+3
    const float4 bf = *(const float4*)(bias + lane * 4);
    const double bfa[4] = {(double)bf.x, (double)bf.y, (double)bf.z, (double)bf.w};

    #pragma unroll 1
    for (int tt = 0; tt < 8; ++tt) {
        double s[4], sc[4];
        #pragma unroll
        for (int i = 0; i < 4; ++i) {
            s[i] = 1.0 / (1.0 + exp(-acc[tt][i]));
            sc[i] = s[i] + bfa[i];
        }
        // group top-2 via sorted-pair merge + 3-step butterfly within 8-lane group
        double a1 = fmax(sc[0], sc[1]), a2 = fmin(sc[0], sc[1]);
        double b1 = fmax(sc[2], sc[3]), b2 = fmin(sc[2], sc[3]);
        double t1 = fmax(a1, b1);
        double t2 = fmax(fmin(a1, b1), fmax(a2, b2));
        #pragma unroll
        for (int off = 1; off <= 4; off <<= 1) {
            double o1 = __shfl_xor(t1, off, 64);
            double o2 = __shfl_xor(t2, off, 64);
            double n1 = fmax(t1, o1);
            double n2 = fmax(fmin(t1, o1), fmax(t2, o2));
            t1 = n1; t2 = n2;
        }
        const double gsum = t1 + t2;
        double gsv[8];
        #pragma unroll
        for (int g = 0; g < 8; ++g) gsv[g] = __shfl(gsum, g * 8, 64);
        const int myg = lane >> 3;
        int cnt = 0;
        #pragma unroll
        for (int g = 0; g < 8; ++g)
            cnt += (gsv[g] > gsum || (gsv[g] == gsum && g < myg)) ? 1 : 0;
        const bool sel = (cnt < 4);

        double v[4];
        #pragma unroll
        for (int i = 0; i < 4; ++i) v[i] = sel ? sc[i] : 0.0;

        int idxs[8]; double sigs[8];
        double denom = 0.0;
        #pragma unroll
        for (int r = 0; r < 8; ++r) {
            double bv = v[0]; int bi = 0; double bs = s[0];
            #pragma unroll
            for (int i = 1; i < 4; ++i)
                if (v[i] > bv) { bv = v[i]; bi = i; bs = s[i]; }
            int bidx = (lane << 2) + bi;
            #pragma unroll
            for (int off = 1; off < 64; off <<= 1) {
                double ov = __shfl_xor(bv, off, 64);
                int oi = __shfl_xor(bidx, off, 64);
                double os = __shfl_xor(bs, off, 64);
                if (ov > bv || (ov == bv && oi < bidx)) { bv = ov; bidx = oi; bs = os; }
            }
            idxs[r] = bidx; sigs[r] = bs; denom += bs;
            if ((bidx >> 2) == lane) {
                #pragma unroll
                for (int i = 0; i < 4; ++i)
                    if ((bidx & 3) == i) v[i] = -1.0e300;
            }
        }
        denom += 1e-20;
        const size_t n = (size_t)(m0 + wv * 8 + tt);
        #pragma unroll
        for (int r = 0; r < 8; ++r) {
            if (lane == r) {
                out[n * 8 + r] = (float)idxs[r];
                out[(size_t)NTOK * 8 + n * 8 + r] = (float)(sigs[r] / denom * 2.5);
            }
        }
    }
}

extern "C" void kernel_launch(void* const* d_in, const int* in_sizes, int n_in,
                              void* d_out, int out_size, void* d_ws, size_t ws_size,
                              hipStream_t stream) {
    const float* X = (const float*)d_in[0];
    const float* W = (const float*)d_in[1];
    const float* bias = (const float*)d_in[2];
    float* out = (float*)d_out;
    moe_gate_kernel<<<NTOK / BM, 256, 0, stream>>>(X, W, bias, out);
}

// Round 3
// 951.077 us; speedup vs baseline: 1.9373x; 1.9373x over previous
//
#include <hip/hip_runtime.h>
#include <math.h>

#define NTOK 16384
#define H 4096
#define NE 256
#define BM 32
#define BK 32
#define NTILE (H / BK)
#define EPS_E 4e-5f
#define EPS_G 8e-5f

__global__ void zero_ws(int* ws) { if (threadIdx.x == 0) ws[0] = 0; }

// ---------------- fast fp32 pass with margin flagging ----------------
__global__ __launch_bounds__(256)
void moe_fast(const float* __restrict__ X, const float* __restrict__ W,
              const float* __restrict__ bias, float* __restrict__ out,
              int* __restrict__ ws, int cap)
{
    __shared__ float Xs[BM * BK];   // [token][k]
    __shared__ float Ws[NE * BK];   // [expert][k], k-chunk XOR-swizzled

    const int t = threadIdx.x;
    const int lane = t & 63;
    const int wv = t >> 6;          // wave owns tokens wv*8..+7
    const int m0 = blockIdx.x * BM;

    float acc[8][4];
    #pragma unroll
    for (int i = 0; i < 8; ++i)
        #pragma unroll
        for (int j = 0; j < 4; ++j) acc[i][j] = 0.f;

    const int xr = t >> 3;              // 0..31
    const int xc = (t & 7) << 2;        // 0..28
    const int cpr = (t & 7) ^ (t >> 5); // swizzled chunk pos, same for all 8 W-rows of this thread
    const float* gx = X + (size_t)(m0 + xr) * H + xc;
    const float* gw = W + (size_t)xr * H + xc;

    float4 xv = *(const float4*)gx;
    float4 wr[8];
    #pragma unroll
    for (int p = 0; p < 8; ++p) wr[p] = *(const float4*)(gw + (size_t)(32 * p) * H);

    for (int t0 = 0; t0 < NTILE; ++t0) {
        __syncthreads();
        *(float4*)&Xs[xr * BK + xc] = xv;
        #pragma unroll
        for (int p = 0; p < 8; ++p)
            *(float4*)&Ws[(xr + 32 * p) * BK + 4 * cpr] = wr[p];
        __syncthreads();
        if (t0 + 1 < NTILE) {
            const int off = (t0 + 1) * BK;
            xv = *(const float4*)(gx + off);
            #pragma unroll
            for (int p = 0; p < 8; ++p)
                wr[p] = *(const float4*)(gw + (size_t)(32 * p) * H + off);
        }
        #pragma unroll
        for (int c = 0; c < 8; ++c) {
            float4 wf[4];
            #pragma unroll
            for (int ei = 0; ei < 4; ++ei)
                wf[ei] = *(const float4*)&Ws[(4 * lane + ei) * BK + 4 * (c ^ (lane & 7))];
            float4 xf[8];
            #pragma unroll
            for (int mi = 0; mi < 8; ++mi)
                xf[mi] = *(const float4*)&Xs[(wv * 8 + mi) * BK + 4 * c];
            #pragma unroll
            for (int mi = 0; mi < 8; ++mi) {
                const float* xp = (const float*)&xf[mi];
                #pragma unroll
                for (int ei = 0; ei < 4; ++ei) {
                    const float* wp = (const float*)&wf[ei];
                    #pragma unroll
                    for (int kk = 0; kk < 4; ++kk)
                        acc[mi][ei] = fmaf(xp[kk], wp[kk], acc[mi][ei]);
                }
            }
        }
    }

    // ---- fp32 routing epilogue with margin flagging
    const float4 bf4 = *(const float4*)(bias + lane * 4);
    const float bfa[4] = {bf4.x, bf4.y, bf4.z, bf4.w};

    #pragma unroll 1
    for (int tt = 0; tt < 8; ++tt) {
        float s[4], sc[4];
        #pragma unroll
        for (int i = 0; i < 4; ++i) {
            s[i] = 1.f / (1.f + expf(-acc[tt][i]));
            sc[i] = s[i] + bfa[i];
        }
        float a1 = fmaxf(sc[0], sc[1]), a2 = fminf(sc[0], sc[1]);
        float b1 = fmaxf(sc[2], sc[3]), b2 = fminf(sc[2], sc[3]);
        float t1 = fmaxf(a1, b1);
        float t2 = fmaxf(fminf(a1, b1), fmaxf(a2, b2));
        #pragma unroll
        for (int off = 1; off <= 4; off <<= 1) {
            float o1 = __shfl_xor(t1, off, 64);
            float o2 = __shfl_xor(t2, off, 64);
            float n1 = fmaxf(t1, o1);
            float n2 = fmaxf(fminf(t1, o1), fmaxf(t2, o2));
            t1 = n1; t2 = n2;
        }
        const float gsum = t1 + t2;
        float gsv[8];
        #pragma unroll
        for (int g = 0; g < 8; ++g) gsv[g] = __shfl(gsum, g * 8, 64);

        float minsel = 3e38f, maxuns = -3e38f;
        bool sel = false;
        const int myg = lane >> 3;
        #pragma unroll
        for (int g = 0; g < 8; ++g) {
            int cg = 0;
            #pragma unroll
            for (int g2 = 0; g2 < 8; ++g2)
                cg += (gsv[g2] > gsv[g] || (gsv[g2] == gsv[g] && g2 < g)) ? 1 : 0;
            const bool sg = (cg < 4);
            if (sg) minsel = fminf(minsel, gsv[g]); else maxuns = fmaxf(maxuns, gsv[g]);
            if (myg == g) sel = sg;
        }
        bool flag = (minsel - maxuns) < EPS_G;

        float v[4];
        #pragma unroll
        for (int i = 0; i < 4; ++i) v[i] = sel ? sc[i] : 0.f;

        int idxs[8]; float sigs[8];
        float denom = 0.f, prevv = 0.f;
        #pragma unroll
        for (int r = 0; r < 9; ++r) {
            float bv = v[0]; int bi = 0; float bs = s[0];
            #pragma unroll
            for (int i = 1; i < 4; ++i)
                if (v[i] > bv) { bv = v[i]; bi = i; bs = s[i]; }
            int bidx = (lane << 2) + bi;
            #pragma unroll
            for (int off = 1; off < 64; off <<= 1) {
                float ov = __shfl_xor(bv, off, 64);
                int  oi = __shfl_xor(bidx, off, 64);
                float os = __shfl_xor(bs, off, 64);
                if (ov > bv || (ov == bv && oi < bidx)) { bv = ov; bidx = oi; bs = os; }
            }
            if (r > 0) flag = flag || ((prevv - bv) < EPS_E);
            prevv = bv;
            if (r < 8) {
                idxs[r] = bidx; sigs[r] = bs; denom += bs;
                if ((bidx >> 2) == lane) {
                    #pragma unroll
                    for (int i = 0; i < 4; ++i)
                        if ((bidx & 3) == i) v[i] = -3e38f;
                }
            }
        }
        denom += 1e-20f;
        const int n = m0 + wv * 8 + tt;
        #pragma unroll
        for (int r = 0; r < 8; ++r)
            if (lane == r) {
                out[n * 8 + r] = (float)idxs[r];
                out[NTOK * 8 + n * 8 + r] = sigs[r] / denom * 2.5f;
            }
        if (flag && lane == 0) {
            int slot = atomicAdd(ws, 1);
            if (slot < cap) ws[16 + slot] = n;
        }
    }
}

// ---------------- exact fp64 fixup for flagged tokens ----------------
__global__ __launch_bounds__(256)
void moe_fix(const float* __restrict__ X, const float* __restrict__ W,
             const float* __restrict__ bias, float* __restrict__ out,
             const int* __restrict__ ws, int cap)
{
    __shared__ double Xd[H];
    __shared__ double Ld[NE];
    const int t = threadIdx.x;
    const int lane = t & 63;
    const int wv = t >> 6;
    int count = ws[0]; if (count > cap) count = cap;

    for (int i = blockIdx.x; i < count; i += (int)gridDim.x) {
        const int n = ws[16 + i];
        __syncthreads();
        const float* xrow = X + (size_t)n * H;
        for (int k = t * 4; k < H; k += 1024) {
            float4 x4 = *(const float4*)(xrow + k);
            Xd[k] = (double)x4.x; Xd[k + 1] = (double)x4.y;
            Xd[k + 2] = (double)x4.z; Xd[k + 3] = (double)x4.w;
        }
        __syncthreads();
        #pragma unroll 1
        for (int cc = 0; cc < 16; ++cc) {
            const int e0 = wv * 64 + cc * 4;
            double a[4] = {0.0, 0.0, 0.0, 0.0};
            for (int j = 0; j < 16; ++j) {
                const int kb = (lane + 64 * j) * 4;
                const double x0 = Xd[kb], x1 = Xd[kb + 1], x2 = Xd[kb + 2], x3 = Xd[kb + 3];
                #pragma unroll
                for (int ee = 0; ee < 4; ++ee) {
                    float4 w4 = *(const float4*)(W + (size_t)(e0 + ee) * H + kb);
                    a[ee] = fma(x0, (double)w4.x, a[ee]);
                    a[ee] = fma(x1, (double)w4.y, a[ee]);
                    a[ee] = fma(x2, (double)w4.z, a[ee]);
                    a[ee] = fma(x3, (double)w4.w, a[ee]);
                }
            }
            #pragma unroll
            for (int ee = 0; ee < 4; ++ee)
                #pragma unroll
                for (int off = 1; off < 64; off <<= 1)
                    a[ee] += __shfl_xor(a[ee], off, 64);
            if (lane == 0) { Ld[e0] = a[0]; Ld[e0 + 1] = a[1]; Ld[e0 + 2] = a[2]; Ld[e0 + 3] = a[3]; }
        }
        __syncthreads();
        if (wv == 0) {
            double s[4], sc[4];
            #pragma unroll
            for (int ii = 0; ii < 4; ++ii) {
                const double L = Ld[lane * 4 + ii];
                s[ii] = 1.0 / (1.0 + exp(-L));
                sc[ii] = s[ii] + (double)bias[lane * 4 + ii];
            }
            double a1 = fmax(sc[0], sc[1]), a2 = fmin(sc[0], sc[1]);
            double b1 = fmax(sc[2], sc[3]), b2 = fmin(sc[2], sc[3]);
            double t1 = fmax(a1, b1);
            double t2 = fmax(fmin(a1, b1), fmax(a2, b2));
            #pragma unroll
            for (int off = 1; off <= 4; off <<= 1) {
                double o1 = __shfl_xor(t1, off, 64);
                double o2 = __shfl_xor(t2, off, 64);
                double n1 = fmax(t1, o1);
                double n2 = fmax(fmin(t1, o1), fmax(t2, o2));
                t1 = n1; t2 = n2;
            }
            const double gsum = t1 + t2;
            double gsv[8];
            #pragma unroll
            for (int g = 0; g < 8; ++g) gsv[g] = __shfl(gsum, g * 8, 64);
            const int myg = lane >> 3;
            int cnt = 0;
            #pragma unroll
            for (int g = 0; g < 8; ++g)
                cnt += (gsv[g] > gsum || (gsv[g] == gsum && g < myg)) ? 1 : 0;
            const bool sel = (cnt < 4);

            double v[4];
            #pragma unroll
            for (int ii = 0; ii < 4; ++ii) v[ii] = sel ? sc[ii] : 0.0;

            int idxs[8]; double sigs[8];
            double denom = 0.0;
            #pragma unroll
            for (int r = 0; r < 8; ++r) {
                double bv = v[0]; int bi = 0; double bs = s[0];
                #pragma unroll
                for (int ii = 1; ii < 4; ++ii)
                    if (v[ii] > bv) { bv = v[ii]; bi = ii; bs = s[ii]; }
                int bidx = (lane << 2) + bi;
                #pragma unroll
                for (int off = 1; off < 64; off <<= 1) {
                    double ov = __shfl_xor(bv, off, 64);
                    int oi = __shfl_xor(bidx, off, 64);
                    double os = __shfl_xor(bs, off, 64);
                    if (ov > bv || (ov == bv && oi < bidx)) { bv = ov; bidx = oi; bs = os; }
                }
                idxs[r] = bidx; sigs[r] = bs; denom += bs;
                if ((bidx >> 2) == lane) {
                    #pragma unroll
                    for (int ii = 0; ii < 4; ++ii)
                        if ((bidx & 3) == ii) v[ii] = -1.0e300;
                }
            }
            denom += 1e-20;
            #pragma unroll
            for (int r = 0; r < 8; ++r)
                if (lane == r) {
                    out[n * 8 + r] = (float)idxs[r];
                    out[NTOK * 8 + n * 8 + r] = (float)(sigs[r] / denom * 2.5);
                }
        }
    }
}

extern "C" void kernel_launch(void* const* d_in, const int* in_sizes, int n_in,
                              void* d_out, int out_size, void* d_ws, size_t ws_size,
                              hipStream_t stream) {
    const float* X = (const float*)d_in[0];
    const float* W = (const float*)d_in[1];
    const float* bias = (const float*)d_in[2];
    float* out = (float*)d_out;
    int* ws = (int*)d_ws;
    int cap = NTOK;
    size_t avail = (ws_size > 64) ? (ws_size - 64) / sizeof(int) : 0;
    if ((size_t)cap > avail) cap = (int)avail;
    zero_ws<<<1, 64, 0, stream>>>(ws);
    moe_fast<<<NTOK / BM, 256, 0, stream>>>(X, W, bias, out, ws, cap);
    moe_fix<<<1024, 256, 0, stream>>>(X, W, bias, out, ws, cap);
}

// Round 4
// 336.834 us; speedup vs baseline: 5.4701x; 2.8236x over previous
//
#include <hip/hip_runtime.h>
#include <math.h>

#define NTOK 16384
#define H 4096
#define NE 256
#define BM 32
#define BK 64
#define NKT (H / BK)
#define EPS_E 6e-5f
#define EPS_G 1.2e-4f

typedef __attribute__((ext_vector_type(8))) short short8;
typedef __attribute__((ext_vector_type(4))) float f32x4;

__device__ __forceinline__ unsigned short f2bf(float x) {
    union { float f; unsigned u; } v; v.f = x;
    unsigned r = v.u + 0x7FFF + ((v.u >> 16) & 1);
    return (unsigned short)(r >> 16);
}
__device__ __forceinline__ float bf2f(unsigned short h) {
    union { float f; unsigned u; } v; v.u = ((unsigned)h) << 16;
    return v.f;
}

__global__ void zero_ws(int* ws) { if (threadIdx.x == 0) ws[0] = 0; }

// ---------------- W split: fp32 -> bf16 hi/lo ----------------
__global__ __launch_bounds__(256)
void split_w(const float* __restrict__ W, unsigned short* __restrict__ whi,
             unsigned short* __restrict__ wlo)
{
    const int i = (blockIdx.x * 256 + threadIdx.x) * 4;
    float4 w4 = *(const float4*)(W + i);
    const float wv[4] = {w4.x, w4.y, w4.z, w4.w};
    ushort4 hh, ll;
    unsigned short* hp = (unsigned short*)&hh;
    unsigned short* lp = (unsigned short*)&ll;
    #pragma unroll
    for (int j = 0; j < 4; ++j) {
        unsigned short h = f2bf(wv[j]);
        hp[j] = h;
        lp[j] = f2bf(wv[j] - bf2f(h));
    }
    *(ushort4*)(whi + i) = hh;
    *(ushort4*)(wlo + i) = ll;
}

// ---------------- fast pass: split-bf16 MFMA + routing + flags ----------------
__global__ __launch_bounds__(256)
void moe_mfma(const float* __restrict__ X, const unsigned short* __restrict__ Whi,
              const unsigned short* __restrict__ Wlo, const float* __restrict__ bias,
              float* __restrict__ out, int* __restrict__ ws, int cap)
{
    __shared__ unsigned short smem[2 * BM * BK + 2 * NE * BK];  // 73728 B
    unsigned short* xh = smem;                  // [32][64] bf16, swizzled
    unsigned short* xl = smem + BM * BK;        // [32][64]
    unsigned short* wh = smem + 2 * BM * BK;    // [256][64]
    unsigned short* wl = wh + NE * BK;          // [256][64]
    float* Ls = (float*)wh;                     // [32][260] logits (reuse W area)

    const int t = threadIdx.x;
    const int lane = t & 63;
    const int wv = t >> 6;
    const int m0 = blockIdx.x * BM;

    f32x4 acc[2][4];
    #pragma unroll
    for (int a = 0; a < 2; ++a)
        #pragma unroll
        for (int b = 0; b < 4; ++b) acc[a][b] = (f32x4){0.f, 0.f, 0.f, 0.f};

    // X staging coords (fp32 -> split -> swizzled ds_write)
    const int xrow = t >> 3;                 // 0..31
    const int xc = t & 7;                    // logical chunk
    const int xpos = xc ^ (xrow & 7);        // swizzled position
    const float* gx = X + (size_t)(m0 + xrow) * H + xc * 8;

    // W gload coords: lane l -> LDS row (+8i), pos l&7; source chunk pre-swizzled
    const int wr0 = wv * 64 + (lane >> 3);
    const int wc = (lane & 7) ^ ((lane >> 3) & 7);   // constant over i (8i keeps row&7)
    const unsigned short* gwh = Whi + (size_t)wr0 * H + wc * 8;
    const unsigned short* gwl = Wlo + (size_t)wr0 * H + wc * 8;

    // MFMA fragment coords
    const int fr = lane & 15;
    const int fq = lane >> 4;

    for (int kt = 0; kt < NKT; ++kt) {
        const int k0 = kt * BK;
        // ---- stage W via global_load_lds (linear dest, pre-swizzled source)
        #pragma unroll
        for (int i = 0; i < 8; ++i) {
            __builtin_amdgcn_global_load_lds(
                (const __attribute__((address_space(1))) void*)(gwh + (size_t)(8 * i) * H + k0),
                (__attribute__((address_space(3))) void*)&wh[(wv * 64 + 8 * i) * BK], 16, 0, 0);
            __builtin_amdgcn_global_load_lds(
                (const __attribute__((address_space(1))) void*)(gwl + (size_t)(8 * i) * H + k0),
                (__attribute__((address_space(3))) void*)&wl[(wv * 64 + 8 * i) * BK], 16, 0, 0);
        }
        // ---- stage X: load fp32, split, swizzled write
        float4 xa = *(const float4*)(gx + k0);
        float4 xb = *(const float4*)(gx + k0 + 4);
        const float xv[8] = {xa.x, xa.y, xa.z, xa.w, xb.x, xb.y, xb.z, xb.w};
        short8 h8, l8;
        #pragma unroll
        for (int j = 0; j < 8; ++j) {
            unsigned short h = f2bf(xv[j]);
            h8[j] = (short)h;
            l8[j] = (short)f2bf(xv[j] - bf2f(h));
        }
        *(short8*)&xh[xrow * BK + xpos * 8] = h8;
        *(short8*)&xl[xrow * BK + xpos * 8] = l8;
        __syncthreads();
        // ---- compute: 48 MFMA per wave
        #pragma unroll
        for (int kk = 0; kk < 2; ++kk) {
            const int c = kk * 4 + fq;
            short8 ah[2], al[2], bh[4], bl[4];
            #pragma unroll
            for (int mt = 0; mt < 2; ++mt) {
                const int r = mt * 16 + fr;
                const int idx = r * BK + (c ^ (r & 7)) * 8;
                ah[mt] = *(const short8*)&xh[idx];
                al[mt] = *(const short8*)&xl[idx];
            }
            #pragma unroll
            for (int nt = 0; nt < 4; ++nt) {
                const int r = wv * 64 + nt * 16 + fr;
                const int idx = r * BK + (c ^ (r & 7)) * 8;
                bh[nt] = *(const short8*)&wh[idx];
                bl[nt] = *(const short8*)&wl[idx];
            }
            #pragma unroll
            for (int mt = 0; mt < 2; ++mt)
                #pragma unroll
                for (int nt = 0; nt < 4; ++nt) {
                    acc[mt][nt] = __builtin_amdgcn_mfma_f32_16x16x32_bf16(ah[mt], bh[nt], acc[mt][nt], 0, 0, 0);
                    acc[mt][nt] = __builtin_amdgcn_mfma_f32_16x16x32_bf16(ah[mt], bl[nt], acc[mt][nt], 0, 0, 0);
                    acc[mt][nt] = __builtin_amdgcn_mfma_f32_16x16x32_bf16(al[mt], bh[nt], acc[mt][nt], 0, 0, 0);
                }
        }
        __syncthreads();
    }

    // ---- dump logits to LDS [32][260] (over W area)
    #pragma unroll
    for (int mt = 0; mt < 2; ++mt)
        #pragma unroll
        for (int nt = 0; nt < 4; ++nt)
            #pragma unroll
            for (int r = 0; r < 4; ++r)
                Ls[(mt * 16 + fq * 4 + r) * 260 + (wv * 64 + nt * 16 + fr)] = acc[mt][nt][r];
    __syncthreads();

    // ---- routing (R3-verified epilogue), wave wv owns tokens wv*8..+7
    const float4 bf4 = *(const float4*)(bias + lane * 4);
    const float bfa[4] = {bf4.x, bf4.y, bf4.z, bf4.w};

    #pragma unroll 1
    for (int tt = 0; tt < 8; ++tt) {
        const int tok = wv * 8 + tt;
        const float4 lg = *(const float4*)&Ls[tok * 260 + lane * 4];
        const float lga[4] = {lg.x, lg.y, lg.z, lg.w};
        float s[4], sc[4];
        #pragma unroll
        for (int i = 0; i < 4; ++i) {
            s[i] = 1.f / (1.f + expf(-lga[i]));
            sc[i] = s[i] + bfa[i];
        }
        float a1 = fmaxf(sc[0], sc[1]), a2 = fminf(sc[0], sc[1]);
        float b1 = fmaxf(sc[2], sc[3]), b2 = fminf(sc[2], sc[3]);
        float t1 = fmaxf(a1, b1);
        float t2 = fmaxf(fminf(a1, b1), fmaxf(a2, b2));
        #pragma unroll
        for (int off = 1; off <= 4; off <<= 1) {
            float o1 = __shfl_xor(t1, off, 64);
            float o2 = __shfl_xor(t2, off, 64);
            float n1 = fmaxf(t1, o1);
            float n2 = fmaxf(fminf(t1, o1), fmaxf(t2, o2));
            t1 = n1; t2 = n2;
        }
        const float gsum = t1 + t2;
        float gsv[8];
        #pragma unroll
        for (int g = 0; g < 8; ++g) gsv[g] = __shfl(gsum, g * 8, 64);

        float minsel = 3e38f, maxuns = -3e38f;
        bool sel = false;
        const int myg = lane >> 3;
        #pragma unroll
        for (int g = 0; g < 8; ++g) {
            int cg = 0;
            #pragma unroll
            for (int g2 = 0; g2 < 8; ++g2)
                cg += (gsv[g2] > gsv[g] || (gsv[g2] == gsv[g] && g2 < g)) ? 1 : 0;
            const bool sg = (cg < 4);
            if (sg) minsel = fminf(minsel, gsv[g]); else maxuns = fmaxf(maxuns, gsv[g]);
            if (myg == g) sel = sg;
        }
        bool flag = (minsel - maxuns) < EPS_G;

        float v[4];
        #pragma unroll
        for (int i = 0; i < 4; ++i) v[i] = sel ? sc[i] : 0.f;

        int idxs[8]; float sigs[8];
        float denom = 0.f, prevv = 0.f;
        #pragma unroll
        for (int r = 0; r < 9; ++r) {
            float bv = v[0]; int bi = 0; float bs = s[0];
            #pragma unroll
            for (int i = 1; i < 4; ++i)
                if (v[i] > bv) { bv = v[i]; bi = i; bs = s[i]; }
            int bidx = (lane << 2) + bi;
            #pragma unroll
            for (int off = 1; off < 64; off <<= 1) {
                float ov = __shfl_xor(bv, off, 64);
                int  oi = __shfl_xor(bidx, off, 64);
                float os = __shfl_xor(bs, off, 64);
                if (ov > bv || (ov == bv && oi < bidx)) { bv = ov; bidx = oi; bs = os; }
            }
            if (r > 0) flag = flag || ((prevv - bv) < EPS_E);
            prevv = bv;
            if (r < 8) {
                idxs[r] = bidx; sigs[r] = bs; denom += bs;
                if ((bidx >> 2) == lane) {
                    #pragma unroll
                    for (int i = 0; i < 4; ++i)
                        if ((bidx & 3) == i) v[i] = -3e38f;
                }
            }
        }
        denom += 1e-20f;
        const int n = m0 + tok;
        #pragma unroll
        for (int r = 0; r < 8; ++r)
            if (lane == r) {
                out[n * 8 + r] = (float)idxs[r];
                out[NTOK * 8 + n * 8 + r] = sigs[r] / denom * 2.5f;
            }
        if (flag && lane == 0) {
            int slot = atomicAdd(ws, 1);
            if (slot < cap) ws[16 + slot] = n;
        }
    }
}

// ---------------- exact fp64 fixup for flagged tokens (R3-verified) ----------------
__global__ __launch_bounds__(256)
void moe_fix(const float* __restrict__ X, const float* __restrict__ W,
             const float* __restrict__ bias, float* __restrict__ out,
             const int* __restrict__ ws, int cap)
{
    __shared__ double Xd[H];
    __shared__ double Ld[NE];
    const int t = threadIdx.x;
    const int lane = t & 63;
    const int wv = t >> 6;
    int count = ws[0]; if (count > cap) count = cap;

    for (int i = blockIdx.x; i < count; i += (int)gridDim.x) {
        const int n = ws[16 + i];
        __syncthreads();
        const float* xrow = X + (size_t)n * H;
        for (int k = t * 4; k < H; k += 1024) {
            float4 x4 = *(const float4*)(xrow + k);
            Xd[k] = (double)x4.x; Xd[k + 1] = (double)x4.y;
            Xd[k + 2] = (double)x4.z; Xd[k + 3] = (double)x4.w;
        }
        __syncthreads();
        #pragma unroll 1
        for (int cc = 0; cc < 16; ++cc) {
            const int e0 = wv * 64 + cc * 4;
            double a[4] = {0.0, 0.0, 0.0, 0.0};
            for (int j = 0; j < 16; ++j) {
                const int kb = (lane + 64 * j) * 4;
                const double x0 = Xd[kb], x1 = Xd[kb + 1], x2 = Xd[kb + 2], x3 = Xd[kb + 3];
                #pragma unroll
                for (int ee = 0; ee < 4; ++ee) {
                    float4 w4 = *(const float4*)(W + (size_t)(e0 + ee) * H + kb);
                    a[ee] = fma(x0, (double)w4.x, a[ee]);
                    a[ee] = fma(x1, (double)w4.y, a[ee]);
                    a[ee] = fma(x2, (double)w4.z, a[ee]);
                    a[ee] = fma(x3, (double)w4.w, a[ee]);
                }
            }
            #pragma unroll
            for (int ee = 0; ee < 4; ++ee)
                #pragma unroll
                for (int off = 1; off < 64; off <<= 1)
                    a[ee] += __shfl_xor(a[ee], off, 64);
            if (lane == 0) { Ld[e0] = a[0]; Ld[e0 + 1] = a[1]; Ld[e0 + 2] = a[2]; Ld[e0 + 3] = a[3]; }
        }
        __syncthreads();
        if (wv == 0) {
            double s[4], sc[4];
            #pragma unroll
            for (int ii = 0; ii < 4; ++ii) {
                const double L = Ld[lane * 4 + ii];
                s[ii] = 1.0 / (1.0 + exp(-L));
                sc[ii] = s[ii] + (double)bias[lane * 4 + ii];
            }
            double a1 = fmax(sc[0], sc[1]), a2 = fmin(sc[0], sc[1]);
            double b1 = fmax(sc[2], sc[3]), b2 = fmin(sc[2], sc[3]);
            double t1 = fmax(a1, b1);
            double t2 = fmax(fmin(a1, b1), fmax(a2, b2));
            #pragma unroll
            for (int off = 1; off <= 4; off <<= 1) {
                double o1 = __shfl_xor(t1, off, 64);
                double o2 = __shfl_xor(t2, off, 64);
                double n1 = fmax(t1, o1);
                double n2 = fmax(fmin(t1, o1), fmax(t2, o2));
                t1 = n1; t2 = n2;
            }
            const double gsum = t1 + t2;
            double gsv[8];
            #pragma unroll
            for (int g = 0; g < 8; ++g) gsv[g] = __shfl(gsum, g * 8, 64);
            const int myg = lane >> 3;
            int cnt = 0;
            #pragma unroll
            for (int g = 0; g < 8; ++g)
                cnt += (gsv[g] > gsum || (gsv[g] == gsum && g < myg)) ? 1 : 0;
            const bool sel = (cnt < 4);

            double v[4];
            #pragma unroll
            for (int ii = 0; ii < 4; ++ii) v[ii] = sel ? sc[ii] : 0.0;

            int idxs[8]; double sigs[8];
            double denom = 0.0;
            #pragma unroll
            for (int r = 0; r < 8; ++r) {
                double bv = v[0]; int bi = 0; double bs = s[0];
                #pragma unroll
                for (int ii = 1; ii < 4; ++ii)
                    if (v[ii] > bv) { bv = v[ii]; bi = ii; bs = s[ii]; }
                int bidx = (lane << 2) + bi;
                #pragma unroll
                for (int off = 1; off < 64; off <<= 1) {
                    double ov = __shfl_xor(bv, off, 64);
                    int oi = __shfl_xor(bidx, off, 64);
                    double os = __shfl_xor(bs, off, 64);
                    if (ov > bv || (ov == bv && oi < bidx)) { bv = ov; bidx = oi; bs = os; }
                }
                idxs[r] = bidx; sigs[r] = bs; denom += bs;
                if ((bidx >> 2) == lane) {
                    #pragma unroll
                    for (int ii = 0; ii < 4; ++ii)
                        if ((bidx & 3) == ii) v[ii] = -1.0e300;
                }
            }
            denom += 1e-20;
            #pragma unroll
            for (int r = 0; r < 8; ++r)
                if (lane == r) {
                    out[n * 8 + r] = (float)idxs[r];
                    out[NTOK * 8 + n * 8 + r] = (float)(sigs[r] / denom * 2.5);
                }
        }
    }
}

// ---------------- fallback: R2 exact-fp64 kernel (if ws too small) ----------------
#define FXP 34
#define FEP 260
__global__ __launch_bounds__(256)
void moe_fb(const float* __restrict__ X, const float* __restrict__ W,
            const float* __restrict__ bias, float* __restrict__ out)
{
    __shared__ double Xs[16 * FXP];
    __shared__ double Ws[16 * FEP];
    const int t = threadIdx.x;
    const int lane = t & 63;
    const int wv = t >> 6;
    const int m0 = blockIdx.x * BM;
    double acc[8][4];
    #pragma unroll
    for (int i = 0; i < 8; ++i)
        #pragma unroll
        for (int j = 0; j < 4; ++j) acc[i][j] = 0.0;
    const int xm = t >> 3, xk = (t & 7) * 2;
    const int we = t >> 2, wk = (t & 3) * 4;
    const float* gx = X + (size_t)(m0 + xm) * H + xk;
    const float* gw = W + (size_t)we * H + wk;
    float2 xreg = *(const float2*)(gx);
    float4 wreg[4];
    #pragma unroll
    for (int p = 0; p < 4; ++p) wreg[p] = *(const float4*)(gw + (size_t)(64 * p) * H);
    const int NT = H / 16;
    for (int t0 = 0; t0 < NT; ++t0) {
        __syncthreads();
        Xs[(xk + 0) * FXP + xm] = (double)xreg.x;
        Xs[(xk + 1) * FXP + xm] = (double)xreg.y;
        #pragma unroll
        for (int p = 0; p < 4; ++p) {
            const int e = we + 64 * p;
            Ws[(wk + 0) * FEP + e] = (double)wreg[p].x;
            Ws[(wk + 1) * FEP + e] = (double)wreg[p].y;
            Ws[(wk + 2) * FEP + e] = (double)wreg[p].z;
            Ws[(wk + 3) * FEP + e] = (double)wreg[p].w;
        }
        __syncthreads();
        if (t0 + 1 < NT) {
            const int off = (t0 + 1) * 16;
            xreg = *(const float2*)(gx + off);
            #pragma unroll
            for (int p = 0; p < 4; ++p) wreg[p] = *(const float4*)(gw + (size_t)(64 * p) * H + off);
        }
        #pragma unroll
        for (int j = 0; j < 16; ++j) {
            const double* xrow = &Xs[j * FXP + wv * 8];
            const double2 wa = *(const double2*)&Ws[j * FEP + lane * 4];
            const double2 wb = *(const double2*)&Ws[j * FEP + lane * 4 + 2];
            const double ws4[4] = {wa.x, wa.y, wb.x, wb.y};
            #pragma unroll
            for (int mi = 0; mi < 8; ++mi)
                #pragma unroll
                for (int ei = 0; ei < 4; ++ei)
                    acc[mi][ei] = fma(xrow[mi], ws4[ei], acc[mi][ei]);
        }
    }
    const float4 bf = *(const float4*)(bias + lane * 4);
    const double bfa[4] = {(double)bf.x, (double)bf.y, (double)bf.z, (double)bf.w};
    #pragma unroll 1
    for (int tt = 0; tt < 8; ++tt) {
        double s[4], sc[4];
        #pragma unroll
        for (int i = 0; i < 4; ++i) {
            s[i] = 1.0 / (1.0 + exp(-acc[tt][i]));
            sc[i] = s[i] + bfa[i];
        }
        double a1 = fmax(sc[0], sc[1]), a2 = fmin(sc[0], sc[1]);
        double b1 = fmax(sc[2], sc[3]), b2 = fmin(sc[2], sc[3]);
        double t1 = fmax(a1, b1);
        double t2 = fmax(fmin(a1, b1), fmax(a2, b2));
        #pragma unroll
        for (int off = 1; off <= 4; off <<= 1) {
            double o1 = __shfl_xor(t1, off, 64);
            double o2 = __shfl_xor(t2, off, 64);
            double n1 = fmax(t1, o1);
            double n2 = fmax(fmin(t1, o1), fmax(t2, o2));
            t1 = n1; t2 = n2;
        }
        const double gsum = t1 + t2;
        double gsv[8];
        #pragma unroll
        for (int g = 0; g < 8; ++g) gsv[g] = __shfl(gsum, g * 8, 64);
        const int myg = lane >> 3;
        int cnt = 0;
        #pragma unroll
        for (int g = 0; g < 8; ++g)
            cnt += (gsv[g] > gsum || (gsv[g] == gsum && g < myg)) ? 1 : 0;
        const bool sel = (cnt < 4);
        double v[4];
        #pragma unroll
        for (int i = 0; i < 4; ++i) v[i] = sel ? sc[i] : 0.0;
        int idxs[8]; double sigs[8];
        double denom = 0.0;
        #pragma unroll
        for (int r = 0; r < 8; ++r) {
            double bv = v[0]; int bi = 0; double bs = s[0];
            #pragma unroll
            for (int i = 1; i < 4; ++i)
                if (v[i] > bv) { bv = v[i]; bi = i; bs = s[i]; }
            int bidx = (lane << 2) + bi;
            #pragma unroll
            for (int off = 1; off < 64; off <<= 1) {
                double ov = __shfl_xor(bv, off, 64);
                int oi = __shfl_xor(bidx, off, 64);
                double os = __shfl_xor(bs, off, 64);
                if (ov > bv || (ov == bv && oi < bidx)) { bv = ov; bidx = oi; bs = os; }
            }
            idxs[r] = bidx; sigs[r] = bs; denom += bs;
            if ((bidx >> 2) == lane) {
                #pragma unroll
                for (int i = 0; i < 4; ++i)
                    if ((bidx & 3) == i) v[i] = -1.0e300;
            }
        }
        denom += 1e-20;
        const size_t n = (size_t)(m0 + wv * 8 + tt);
        #pragma unroll
        for (int r = 0; r < 8; ++r)
            if (lane == r) {
                out[n * 8 + r] = (float)idxs[r];
                out[(size_t)NTOK * 8 + n * 8 + r] = (float)(sigs[r] / denom * 2.5);
            }
    }
}

extern "C" void kernel_launch(void* const* d_in, const int* in_sizes, int n_in,
                              void* d_out, int out_size, void* d_ws, size_t ws_size,
                              hipStream_t stream) {
    const float* X = (const float*)d_in[0];
    const float* W = (const float*)d_in[1];
    const float* bias = (const float*)d_in[2];
    float* out = (float*)d_out;

    const size_t WBYTES = (size_t)NE * H * sizeof(unsigned short);  // 2 MB each
    const size_t NEED = 65536 + 2 * WBYTES;
    if (ws_size < NEED) {
        moe_fb<<<NTOK / BM, 256, 0, stream>>>(X, W, bias, out);
        return;
    }
    int* ws = (int*)d_ws;
    unsigned short* whi = (unsigned short*)((char*)d_ws + 65536);
    unsigned short* wlo = whi + NE * H;
    const int cap = 65536 / 4 - 16;

    zero_ws<<<1, 64, 0, stream>>>(ws);
    split_w<<<(NE * H) / 1024, 256, 0, stream>>>(W, whi, wlo);
    moe_mfma<<<NTOK / BM, 256, 0, stream>>>(X, whi, wlo, bias, out, ws, cap);
    moe_fix<<<1024, 256, 0, stream>>>(X, W, bias, out, ws, cap);
}

// Round 5
// 292.954 us; speedup vs baseline: 6.2894x; 1.1498x over previous
//
#include <hip/hip_runtime.h>
#include <math.h>

#define NTOK 16384
#define H 4096
#define NE 256
#define BM 64
#define BK 64
#define NKT (H / BK)
#define EPS_E 1.2e-5f
#define EPS_G 2.4e-5f

typedef __attribute__((ext_vector_type(8))) short short8;
typedef __attribute__((ext_vector_type(4))) float f32x4;

__device__ __forceinline__ unsigned short f2bf(float x) {
    union { float f; unsigned u; } v; v.f = x;
    unsigned r = v.u + 0x7FFF + ((v.u >> 16) & 1);
    return (unsigned short)(r >> 16);
}
__device__ __forceinline__ float bf2f(unsigned short h) {
    union { float f; unsigned u; } v; v.u = ((unsigned)h) << 16;
    return v.f;
}

__global__ void zero_ws(int* ws) { if (threadIdx.x == 0) ws[0] = 0; }

__global__ __launch_bounds__(256)
void split_w(const float* __restrict__ W, unsigned short* __restrict__ whi,
             unsigned short* __restrict__ wlo)
{
    const int i = (blockIdx.x * 256 + threadIdx.x) * 4;
    float4 w4 = *(const float4*)(W + i);
    const float wv[4] = {w4.x, w4.y, w4.z, w4.w};
    ushort4 hh, ll;
    unsigned short* hp = (unsigned short*)&hh;
    unsigned short* lp = (unsigned short*)&ll;
    #pragma unroll
    for (int j = 0; j < 4; ++j) {
        unsigned short h = f2bf(wv[j]);
        hp[j] = h;
        lp[j] = f2bf(wv[j] - bf2f(h));
    }
    *(ushort4*)(whi + i) = hh;
    *(ushort4*)(wlo + i) = ll;
}

// ---------------- fast pass: pipelined split-bf16 MFMA ----------------
__global__ __launch_bounds__(512, 2)
void moe_mfma(const float* __restrict__ X, const unsigned short* __restrict__ Whi,
              const unsigned short* __restrict__ Wlo, const float* __restrict__ bias,
              float* __restrict__ out, int* __restrict__ ws, int cap)
{
    __shared__ __align__(16) unsigned short smem[73728];   // 144 KB
    unsigned short* xh  = smem;                 // [64][64]
    unsigned short* xl  = smem + 4096;
    unsigned short* wh0 = smem + 8192;          // [256][64] buf0
    unsigned short* wl0 = smem + 24576;
    unsigned short* wh1 = smem + 40960;         // buf1
    unsigned short* wl1 = smem + 57344;

    const int t = threadIdx.x;
    const int lane = t & 63;
    const int wv = t >> 6;       // 0..7
    const int wr = wv >> 2;      // 0..1 token-half
    const int wc = wv & 3;       // 0..3 expert-quarter
    const int m0 = blockIdx.x * BM;
    const int fr = lane & 15;
    const int fq = lane >> 4;

    f32x4 acc[2][4];
    #pragma unroll
    for (int a = 0; a < 2; ++a)
        #pragma unroll
        for (int b = 0; b < 4; ++b) acc[a][b] = (f32x4){0.f, 0.f, 0.f, 0.f};

    // X staging coords
    const int xrow = t >> 3;                 // 0..63
    const int xch  = t & 7;
    const int xpos = xch ^ (xrow & 7);
    const float* gx = X + (size_t)(m0 + xrow) * H + xch * 8;

    // W gload coords (linear LDS dest, pre-swizzled global source)
    const int wlr = lane >> 3;               // 0..7
    const int wlc = (lane & 7) ^ wlr;
    const unsigned short* gwh = Whi + (size_t)(wv * 8 + wlr) * H + wlc * 8;
    const unsigned short* gwl = Wlo + (size_t)(wv * 8 + wlr) * H + wlc * 8;

    auto issueW = [&](unsigned short* dh, unsigned short* dl, int kt) {
        const size_t k0 = (size_t)kt * BK;
        #pragma unroll
        for (int i = 0; i < 4; ++i) {
            __builtin_amdgcn_global_load_lds(
                (const __attribute__((address_space(1))) void*)(gwh + (size_t)(64 * i) * H + k0),
                (__attribute__((address_space(3))) void*)&dh[(wv * 8 + 64 * i) * BK], 16, 0, 0);
            __builtin_amdgcn_global_load_lds(
                (const __attribute__((address_space(1))) void*)(gwl + (size_t)(64 * i) * H + k0),
                (__attribute__((address_space(3))) void*)&dl[(wv * 8 + 64 * i) * BK], 16, 0, 0);
        }
    };

    auto kstep = [&](float4& xa, float4& xb, const unsigned short* bufh,
                     const unsigned short* bufl, unsigned short* nbufh,
                     unsigned short* nbufl, int ktw, int ktx) {
        // A: split current X regs -> swizzled LDS write
        const float xv[8] = {xa.x, xa.y, xa.z, xa.w, xb.x, xb.y, xb.z, xb.w};
        short8 h8, l8;
        #pragma unroll
        for (int j = 0; j < 8; ++j) {
            unsigned short h = f2bf(xv[j]);
            h8[j] = (short)h;
            l8[j] = (short)f2bf(xv[j] - bf2f(h));
        }
        *(short8*)&xh[xrow * BK + xpos * 8] = h8;
        *(short8*)&xl[xrow * BK + xpos * 8] = l8;
        // B: W(t) landed (issued last step); keep 2 X loads in flight
        asm volatile("s_waitcnt vmcnt(2) lgkmcnt(0)" ::: "memory");
        __builtin_amdgcn_sched_barrier(0);
        __builtin_amdgcn_s_barrier();
        // C: all fragment reads
        short8 fAh[2][2], fAl[2][2], fBh[2][4], fBl[2][4];
        #pragma unroll
        for (int kk = 0; kk < 2; ++kk) {
            const int cc = ((kk * 4 + fq) ^ (fr & 7)) * 8;
            #pragma unroll
            for (int mt = 0; mt < 2; ++mt) {
                const int r = wr * 32 + mt * 16 + fr;
                fAh[kk][mt] = *(const short8*)&xh[r * BK + cc];
                fAl[kk][mt] = *(const short8*)&xl[r * BK + cc];
            }
            #pragma unroll
            for (int nt = 0; nt < 4; ++nt) {
                const int r = wc * 64 + nt * 16 + fr;
                fBh[kk][nt] = *(const short8*)&bufh[r * BK + cc];
                fBl[kk][nt] = *(const short8*)&bufl[r * BK + cc];
            }
        }
        // D: frags in regs; release writers
        asm volatile("s_waitcnt lgkmcnt(0)" ::: "memory");
        __builtin_amdgcn_sched_barrier(0);
        __builtin_amdgcn_s_barrier();
        // E: issue next W (first!) then next-next X
        issueW(nbufh, nbufl, ktw);
        __builtin_amdgcn_sched_barrier(0);
        xa = *(const float4*)(gx + (size_t)ktx * BK);
        xb = *(const float4*)(gx + (size_t)ktx * BK + 4);
        __builtin_amdgcn_sched_barrier(0);
        // F: MFMA cluster
        __builtin_amdgcn_s_setprio(1);
        #pragma unroll
        for (int kk = 0; kk < 2; ++kk)
            #pragma unroll
            for (int mt = 0; mt < 2; ++mt)
                #pragma unroll
                for (int nt = 0; nt < 4; ++nt) {
                    acc[mt][nt] = __builtin_amdgcn_mfma_f32_16x16x32_bf16(fAh[kk][mt], fBh[kk][nt], acc[mt][nt], 0, 0, 0);
                    acc[mt][nt] = __builtin_amdgcn_mfma_f32_16x16x32_bf16(fAh[kk][mt], fBl[kk][nt], acc[mt][nt], 0, 0, 0);
                    acc[mt][nt] = __builtin_amdgcn_mfma_f32_16x16x32_bf16(fAl[kk][mt], fBh[kk][nt], acc[mt][nt], 0, 0, 0);
                }
        __builtin_amdgcn_s_setprio(0);
    };

    // prologue: W(0)->buf0, then X(0), X(1) into regs
    issueW(wh0, wl0, 0);
    __builtin_amdgcn_sched_barrier(0);
    float4 x0a = *(const float4*)(gx);
    float4 x0b = *(const float4*)(gx + 4);
    float4 x1a = *(const float4*)(gx + BK);
    float4 x1b = *(const float4*)(gx + BK + 4);

    for (int kt = 0; kt < NKT; kt += 2) {
        const int k1 = kt + 1;
        const int k2 = (kt + 2 < NKT) ? kt + 2 : 0;
        const int k3 = (kt + 3 < NKT) ? kt + 3 : 0;
        kstep(x0a, x0b, wh0, wl0, wh1, wl1, (k1 < NKT) ? k1 : 0, k2);
        kstep(x1a, x1b, wh1, wl1, wh0, wl0, k2, k3);
    }
    // keep tail prefetch loads alive so vmcnt counts stay exact
    asm volatile("" :: "v"(x0a.x), "v"(x0a.y), "v"(x0a.z), "v"(x0a.w),
                       "v"(x0b.x), "v"(x0b.y), "v"(x0b.z), "v"(x0b.w),
                       "v"(x1a.x), "v"(x1a.y), "v"(x1a.z), "v"(x1a.w),
                       "v"(x1b.x), "v"(x1b.y), "v"(x1b.z), "v"(x1b.w));
    asm volatile("s_waitcnt vmcnt(0) lgkmcnt(0)" ::: "memory");
    __builtin_amdgcn_sched_barrier(0);
    __builtin_amdgcn_s_barrier();

    // ---- dump logits to LDS [64][260] over buf area
    float* Ls = (float*)(smem + 8192);
    #pragma unroll
    for (int mt = 0; mt < 2; ++mt)
        #pragma unroll
        for (int nt = 0; nt < 4; ++nt)
            #pragma unroll
            for (int r = 0; r < 4; ++r)
                Ls[(wr * 32 + mt * 16 + fq * 4 + r) * 260 + (wc * 64 + nt * 16 + fr)] = acc[mt][nt][r];
    __syncthreads();

    // ---- routing (verified epilogue): wave wv owns tokens wv*8..+7
    const float4 bf4 = *(const float4*)(bias + lane * 4);
    const float bfa[4] = {bf4.x, bf4.y, bf4.z, bf4.w};

    #pragma unroll 1
    for (int tt = 0; tt < 8; ++tt) {
        const int tok = wv * 8 + tt;
        const float4 lg = *(const float4*)&Ls[tok * 260 + lane * 4];
        const float lga[4] = {lg.x, lg.y, lg.z, lg.w};
        float s[4], sc[4];
        #pragma unroll
        for (int i = 0; i < 4; ++i) {
            s[i] = 1.f / (1.f + expf(-lga[i]));
            sc[i] = s[i] + bfa[i];
        }
        float a1 = fmaxf(sc[0], sc[1]), a2 = fminf(sc[0], sc[1]);
        float b1 = fmaxf(sc[2], sc[3]), b2 = fminf(sc[2], sc[3]);
        float t1 = fmaxf(a1, b1);
        float t2 = fmaxf(fminf(a1, b1), fmaxf(a2, b2));
        #pragma unroll
        for (int off = 1; off <= 4; off <<= 1) {
            float o1 = __shfl_xor(t1, off, 64);
            float o2 = __shfl_xor(t2, off, 64);
            float n1 = fmaxf(t1, o1);
            float n2 = fmaxf(fminf(t1, o1), fmaxf(t2, o2));
            t1 = n1; t2 = n2;
        }
        const float gsum = t1 + t2;
        float gsv[8];
        #pragma unroll
        for (int g = 0; g < 8; ++g) gsv[g] = __shfl(gsum, g * 8, 64);

        float minsel = 3e38f, maxuns = -3e38f;
        bool sel = false;
        const int myg = lane >> 3;
        #pragma unroll
        for (int g = 0; g < 8; ++g) {
            int cg = 0;
            #pragma unroll
            for (int g2 = 0; g2 < 8; ++g2)
                cg += (gsv[g2] > gsv[g] || (gsv[g2] == gsv[g] && g2 < g)) ? 1 : 0;
            const bool sg = (cg < 4);
            if (sg) minsel = fminf(minsel, gsv[g]); else maxuns = fmaxf(maxuns, gsv[g]);
            if (myg == g) sel = sg;
        }
        bool flag = (minsel - maxuns) < EPS_G;

        float v[4];
        #pragma unroll
        for (int i = 0; i < 4; ++i) v[i] = sel ? sc[i] : 0.f;

        int idxs[8]; float sigs[8];
        float denom = 0.f, prevv = 0.f;
        #pragma unroll
        for (int r = 0; r < 9; ++r) {
            float bv = v[0]; int bi = 0; float bs = s[0];
            #pragma unroll
            for (int i = 1; i < 4; ++i)
                if (v[i] > bv) { bv = v[i]; bi = i; bs = s[i]; }
            int bidx = (lane << 2) + bi;
            #pragma unroll
            for (int off = 1; off < 64; off <<= 1) {
                float ov = __shfl_xor(bv, off, 64);
                int  oi = __shfl_xor(bidx, off, 64);
                float os = __shfl_xor(bs, off, 64);
                if (ov > bv || (ov == bv && oi < bidx)) { bv = ov; bidx = oi; bs = os; }
            }
            if (r > 0) flag = flag || ((prevv - bv) < EPS_E);
            prevv = bv;
            if (r < 8) {
                idxs[r] = bidx; sigs[r] = bs; denom += bs;
                if ((bidx >> 2) == lane) {
                    #pragma unroll
                    for (int i = 0; i < 4; ++i)
                        if ((bidx & 3) == i) v[i] = -3e38f;
                }
            }
        }
        denom += 1e-20f;
        const int n = m0 + tok;
        #pragma unroll
        for (int r = 0; r < 8; ++r)
            if (lane == r) {
                out[n * 8 + r] = (float)idxs[r];
                out[NTOK * 8 + n * 8 + r] = sigs[r] / denom * 2.5f;
            }
        if (flag && lane == 0) {
            int slot = atomicAdd(ws, 1);
            if (slot < cap) ws[16 + slot] = n;
        }
    }
}

// ---------------- exact fp64 fixup for flagged tokens (R3-verified) ----------------
__global__ __launch_bounds__(256)
void moe_fix(const float* __restrict__ X, const float* __restrict__ W,
             const float* __restrict__ bias, float* __restrict__ out,
             const int* __restrict__ ws, int cap)
{
    __shared__ double Xd[H];
    __shared__ double Ld[NE];
    const int t = threadIdx.x;
    const int lane = t & 63;
    const int wv = t >> 6;
    int count = ws[0]; if (count > cap) count = cap;

    for (int i = blockIdx.x; i < count; i += (int)gridDim.x) {
        const int n = ws[16 + i];
        __syncthreads();
        const float* xrow = X + (size_t)n * H;
        for (int k = t * 4; k < H; k += 1024) {
            float4 x4 = *(const float4*)(xrow + k);
            Xd[k] = (double)x4.x; Xd[k + 1] = (double)x4.y;
            Xd[k + 2] = (double)x4.z; Xd[k + 3] = (double)x4.w;
        }
        __syncthreads();
        #pragma unroll 1
        for (int cc = 0; cc < 16; ++cc) {
            const int e0 = wv * 64 + cc * 4;
            double a[4] = {0.0, 0.0, 0.0, 0.0};
            for (int j = 0; j < 16; ++j) {
                const int kb = (lane + 64 * j) * 4;
                const double x0 = Xd[kb], x1 = Xd[kb + 1], x2 = Xd[kb + 2], x3 = Xd[kb + 3];
                #pragma unroll
                for (int ee = 0; ee < 4; ++ee) {
                    float4 w4 = *(const float4*)(W + (size_t)(e0 + ee) * H + kb);
                    a[ee] = fma(x0, (double)w4.x, a[ee]);
                    a[ee] = fma(x1, (double)w4.y, a[ee]);
                    a[ee] = fma(x2, (double)w4.z, a[ee]);
                    a[ee] = fma(x3, (double)w4.w, a[ee]);
                }
            }
            #pragma unroll
            for (int ee = 0; ee < 4; ++ee)
                #pragma unroll
                for (int off = 1; off < 64; off <<= 1)
                    a[ee] += __shfl_xor(a[ee], off, 64);
            if (lane == 0) { Ld[e0] = a[0]; Ld[e0 + 1] = a[1]; Ld[e0 + 2] = a[2]; Ld[e0 + 3] = a[3]; }
        }
        __syncthreads();
        if (wv == 0) {
            double s[4], sc[4];
            #pragma unroll
            for (int ii = 0; ii < 4; ++ii) {
                const double L = Ld[lane * 4 + ii];
                s[ii] = 1.0 / (1.0 + exp(-L));
                sc[ii] = s[ii] + (double)bias[lane * 4 + ii];
            }
            double a1 = fmax(sc[0], sc[1]), a2 = fmin(sc[0], sc[1]);
            double b1 = fmax(sc[2], sc[3]), b2 = fmin(sc[2], sc[3]);
            double t1 = fmax(a1, b1);
            double t2 = fmax(fmin(a1, b1), fmax(a2, b2));
            #pragma unroll
            for (int off = 1; off <= 4; off <<= 1) {
                double o1 = __shfl_xor(t1, off, 64);
                double o2 = __shfl_xor(t2, off, 64);
                double n1 = fmax(t1, o1);
                double n2 = fmax(fmin(t1, o1), fmax(t2, o2));
                t1 = n1; t2 = n2;
            }
            const double gsum = t1 + t2;
            double gsv[8];
            #pragma unroll
            for (int g = 0; g < 8; ++g) gsv[g] = __shfl(gsum, g * 8, 64);
            const int myg = lane >> 3;
            int cnt = 0;
            #pragma unroll
            for (int g = 0; g < 8; ++g)
                cnt += (gsv[g] > gsum || (gsv[g] == gsum && g < myg)) ? 1 : 0;
            const bool sel = (cnt < 4);

            double v[4];
            #pragma unroll
            for (int ii = 0; ii < 4; ++ii) v[ii] = sel ? sc[ii] : 0.0;

            int idxs[8]; double sigs[8];
            double denom = 0.0;
            #pragma unroll
            for (int r = 0; r < 8; ++r) {
                double bv = v[0]; int bi = 0; double bs = s[0];
                #pragma unroll
                for (int ii = 1; ii < 4; ++ii)
                    if (v[ii] > bv) { bv = v[ii]; bi = ii; bs = s[ii]; }
                int bidx = (lane << 2) + bi;
                #pragma unroll
                for (int off = 1; off < 64; off <<= 1) {
                    double ov = __shfl_xor(bv, off, 64);
                    int oi = __shfl_xor(bidx, off, 64);
                    double os = __shfl_xor(bs, off, 64);
                    if (ov > bv || (ov == bv && oi < bidx)) { bv = ov; bidx = oi; bs = os; }
                }
                idxs[r] = bidx; sigs[r] = bs; denom += bs;
                if ((bidx >> 2) == lane) {
                    #pragma unroll
                    for (int ii = 0; ii < 4; ++ii)
                        if ((bidx & 3) == ii) v[ii] = -1.0e300;
                }
            }
            denom += 1e-20;
            #pragma unroll
            for (int r = 0; r < 8; ++r)
                if (lane == r) {
                    out[n * 8 + r] = (float)idxs[r];
                    out[NTOK * 8 + n * 8 + r] = (float)(sigs[r] / denom * 2.5);
                }
        }
    }
}

// ---------------- fallback: exact-fp64 kernel (if ws too small) ----------------
#define FXP 34
#define FEP 260
__global__ __launch_bounds__(256)
void moe_fb(const float* __restrict__ X, const float* __restrict__ W,
            const float* __restrict__ bias, float* __restrict__ out)
{
    __shared__ double Xs[16 * FXP];
    __shared__ double Ws[16 * FEP];
    const int t = threadIdx.x;
    const int lane = t & 63;
    const int wv = t >> 6;
    const int m0 = blockIdx.x * 32;
    double acc[8][4];
    #pragma unroll
    for (int i = 0; i < 8; ++i)
        #pragma unroll
        for (int j = 0; j < 4; ++j) acc[i][j] = 0.0;
    const int xm = t >> 3, xk = (t & 7) * 2;
    const int we = t >> 2, wk = (t & 3) * 4;
    const float* gx = X + (size_t)(m0 + xm) * H + xk;
    const float* gw = W + (size_t)we * H + wk;
    float2 xreg = *(const float2*)(gx);
    float4 wreg[4];
    #pragma unroll
    for (int p = 0; p < 4; ++p) wreg[p] = *(const float4*)(gw + (size_t)(64 * p) * H);
    const int NT = H / 16;
    for (int t0 = 0; t0 < NT; ++t0) {
        __syncthreads();
        Xs[(xk + 0) * FXP + xm] = (double)xreg.x;
        Xs[(xk + 1) * FXP + xm] = (double)xreg.y;
        #pragma unroll
        for (int p = 0; p < 4; ++p) {
            const int e = we + 64 * p;
            Ws[(wk + 0) * FEP + e] = (double)wreg[p].x;
            Ws[(wk + 1) * FEP + e] = (double)wreg[p].y;
            Ws[(wk + 2) * FEP + e] = (double)wreg[p].z;
            Ws[(wk + 3) * FEP + e] = (double)wreg[p].w;
        }
        __syncthreads();
        if (t0 + 1 < NT) {
            const int off = (t0 + 1) * 16;
            xreg = *(const float2*)(gx + off);
            #pragma unroll
            for (int p = 0; p < 4; ++p) wreg[p] = *(const float4*)(gw + (size_t)(64 * p) * H + off);
        }
        #pragma unroll
        for (int j = 0; j < 16; ++j) {
            const double* xrow = &Xs[j * FXP + wv * 8];
            const double2 wa = *(const double2*)&Ws[j * FEP + lane * 4];
            const double2 wb = *(const double2*)&Ws[j * FEP + lane * 4 + 2];
            const double ws4[4] = {wa.x, wa.y, wb.x, wb.y};
            #pragma unroll
            for (int mi = 0; mi < 8; ++mi)
                #pragma unroll
                for (int ei = 0; ei < 4; ++ei)
                    acc[mi][ei] = fma(xrow[mi], ws4[ei], acc[mi][ei]);
        }
    }
    const float4 bf = *(const float4*)(bias + lane * 4);
    const double bfa[4] = {(double)bf.x, (double)bf.y, (double)bf.z, (double)bf.w};
    #pragma unroll 1
    for (int tt = 0; tt < 8; ++tt) {
        double s[4], sc[4];
        #pragma unroll
        for (int i = 0; i < 4; ++i) {
            s[i] = 1.0 / (1.0 + exp(-acc[tt][i]));
            sc[i] = s[i] + bfa[i];
        }
        double a1 = fmax(sc[0], sc[1]), a2 = fmin(sc[0], sc[1]);
        double b1 = fmax(sc[2], sc[3]), b2 = fmin(sc[2], sc[3]);
        double t1 = fmax(a1, b1);
        double t2 = fmax(fmin(a1, b1), fmax(a2, b2));
        #pragma unroll
        for (int off = 1; off <= 4; off <<= 1) {
            double o1 = __shfl_xor(t1, off, 64);
            double o2 = __shfl_xor(t2, off, 64);
            double n1 = fmax(t1, o1);
            double n2 = fmax(fmin(t1, o1), fmax(t2, o2));
            t1 = n1; t2 = n2;
        }
        const double gsum = t1 + t2;
        double gsv[8];
        #pragma unroll
        for (int g = 0; g < 8; ++g) gsv[g] = __shfl(gsum, g * 8, 64);
        const int myg = lane >> 3;
        int cnt = 0;
        #pragma unroll
        for (int g = 0; g < 8; ++g)
            cnt += (gsv[g] > gsum || (gsv[g] == gsum && g < myg)) ? 1 : 0;
        const bool sel = (cnt < 4);
        double v[4];
        #pragma unroll
        for (int i = 0; i < 4; ++i) v[i] = sel ? sc[i] : 0.0;
        int idxs[8]; double sigs[8];
        double denom = 0.0;
        #pragma unroll
        for (int r = 0; r < 8; ++r) {
            double bv = v[0]; int bi = 0; double bs = s[0];
            #pragma unroll
            for (int i = 1; i < 4; ++i)
                if (v[i] > bv) { bv = v[i]; bi = i; bs = s[i]; }
            int bidx = (lane << 2) + bi;
            #pragma unroll
            for (int off = 1; off < 64; off <<= 1) {
                double ov = __shfl_xor(bv, off, 64);
                int oi = __shfl_xor(bidx, off, 64);
                double os = __shfl_xor(bs, off, 64);
                if (ov > bv || (ov == bv && oi < bidx)) { bv = ov; bidx = oi; bs = os; }
            }
            idxs[r] = bidx; sigs[r] = bs; denom += bs;
            if ((bidx >> 2) == lane) {
                #pragma unroll
                for (int i = 0; i < 4; ++i)
                    if ((bidx & 3) == i) v[i] = -1.0e300;
            }
        }
        denom += 1e-20;
        const size_t n = (size_t)(m0 + wv * 8 + tt);
        #pragma unroll
        for (int r = 0; r < 8; ++r)
            if (lane == r) {
                out[n * 8 + r] = (float)idxs[r];
                out[(size_t)NTOK * 8 + n * 8 + r] = (float)(sigs[r] / denom * 2.5);
            }
    }
}

extern "C" void kernel_launch(void* const* d_in, const int* in_sizes, int n_in,
                              void* d_out, int out_size, void* d_ws, size_t ws_size,
                              hipStream_t stream) {
    const float* X = (const float*)d_in[0];
    const float* W = (const float*)d_in[1];
    const float* bias = (const float*)d_in[2];
    float* out = (float*)d_out;

    const size_t WBYTES = (size_t)NE * H * sizeof(unsigned short);
    const size_t NEED = 65536 + 2 * WBYTES;
    if (ws_size < NEED) {
        moe_fb<<<NTOK / 32, 256, 0, stream>>>(X, W, bias, out);
        return;
    }
    int* ws = (int*)d_ws;
    unsigned short* whi = (unsigned short*)((char*)d_ws + 65536);
    unsigned short* wlo = whi + (size_t)NE * H;
    const int cap = 65536 / 4 - 16;

    zero_ws<<<1, 64, 0, stream>>>(ws);
    split_w<<<(NE * H) / 1024, 256, 0, stream>>>(W, whi, wlo);
    moe_mfma<<<NTOK / BM, 512, 0, stream>>>(X, whi, wlo, bias, out, ws, cap);
    moe_fix<<<1024, 256, 0, stream>>>(X, W, bias, out, ws, cap);
}